// Round 2
// baseline (290.534 us; speedup 1.0000x reference)
//
#include <hip/hip_runtime.h>
#include <math.h>

// x[32,4096,32] f32, codebook[256,32] f32
// outputs (concat f32): o_idx[N], o_probs[N*256], o_quants[N*32], o_loss[N]
constexpr int D    = 32;
constexpr int K    = 256;
constexpr int ROWS = 64;   // rows per block (= lanes per wave)
constexpr int CPT  = 64;   // codes per thread (K / 4 waves)

__global__ __launch_bounds__(256) void vq_kernel(
    const float* __restrict__ x,
    const float* __restrict__ cb,
    float* __restrict__ o_idx,
    float* __restrict__ o_probs,
    float* __restrict__ o_quants,
    float* __restrict__ o_loss)
{
    __shared__ float  cn[K];               // per-code squared norms (1 KB)
    __shared__ float4 pbuf[4][ROWS][9];    // per-wave transpose buf, +1 f4 pad (36 KB)
    __shared__ float  mred[4][ROWS];       // cross-wave max
    __shared__ float  sred[4][ROWS];       // cross-wave sum
    __shared__ int    ired[4][ROWS];       // cross-wave argmax

    const int tid = threadIdx.x;
    const int l   = tid & 63;                                      // lane = local row
    const int wu  = __builtin_amdgcn_readfirstlane(tid >> 6);      // wave id, scalar
    const int row = blockIdx.x * ROWS + l;

    // --- per-code squared norm: one code per thread (K == blockDim) ---
    {
        const float4* c4 = reinterpret_cast<const float4*>(cb) + tid * (D / 4);
        float a0 = 0.f, a1 = 0.f, a2 = 0.f, a3 = 0.f;
        #pragma unroll
        for (int i = 0; i < D / 4; ++i) {
            float4 c = c4[i];
            a0 += c.x * c.x; a1 += c.y * c.y; a2 += c.z * c.z; a3 += c.w * c.w;
        }
        cn[tid] = (a0 + a1) + (a2 + a3);
    }

    // --- x row into registers (4 waves load the same 8 KB; L1 dedups) ---
    float xr[D];
    {
        const float4* xv = reinterpret_cast<const float4*>(x) + (size_t)row * (D / 4);
        #pragma unroll
        for (int i = 0; i < D / 4; ++i) {
            float4 v = xv[i];
            xr[4 * i + 0] = v.x; xr[4 * i + 1] = v.y;
            xr[4 * i + 2] = v.z; xr[4 * i + 3] = v.w;
        }
    }
    float xx;
    {
        float a0 = 0.f, a1 = 0.f, a2 = 0.f, a3 = 0.f;
        #pragma unroll
        for (int j = 0; j < D; j += 4) {
            a0 += xr[j] * xr[j];         a1 += xr[j + 1] * xr[j + 1];
            a2 += xr[j + 2] * xr[j + 2]; a3 += xr[j + 3] * xr[j + 3];
        }
        xx = (a0 + a1) + (a2 + a3);
    }
    __syncthreads();   // cn ready

    // --- single distance pass: wave wu covers codes [64*wu, 64*wu+64) ---
    // logits stay register-resident (all indexing static / fully unrolled)
    const int kbase = wu * CPT;
    float lg[CPT];
    #pragma unroll
    for (int j = 0; j < CPT; ++j) {
        const float* c = cb + (kbase + j) * D;   // wave-uniform -> scalar loads
        float d0 = 0.f, d1 = 0.f, d2 = 0.f, d3 = 0.f;
        #pragma unroll
        for (int t = 0; t < D; t += 4) {
            d0 += xr[t] * c[t];         d1 += xr[t + 1] * c[t + 1];
            d2 += xr[t + 2] * c[t + 2]; d3 += xr[t + 3] * c[t + 3];
        }
        float dot = (d0 + d1) + (d2 + d3);
        lg[j] = 2.0f * dot - (xx + cn[kbase + j]);   // = -d2
    }

    // --- local first-max argmax (strictly-greater keeps lowest j) ---
    float m = lg[0]; int bi = 0;
    #pragma unroll
    for (int j = 1; j < CPT; ++j) {
        bool gt = lg[j] > m;
        m  = gt ? lg[j] : m;
        bi = gt ? j : bi;
    }
    mred[wu][l] = m;
    ired[wu][l] = kbase + bi;
    __syncthreads();

    // --- cross-wave max+argmax: ascending wave order keeps first occurrence ---
    float gm = mred[0][l]; int gi = ired[0][l];
    #pragma unroll
    for (int ww = 1; ww < 4; ++ww) {
        float mw = mred[ww][l];
        bool gt  = mw > gm;
        gi = gt ? ired[ww][l] : gi;
        gm = gt ? mw : gm;
    }

    // --- one exp per logit, stored in place; local sum ---
    float s = 0.f;
    #pragma unroll
    for (int j = 0; j < CPT; ++j) {
        float e = __expf(lg[j] - gm);
        lg[j] = e;
        s += e;
    }
    sred[wu][l] = s;
    __syncthreads();
    float gs = (sred[0][l] + sred[1][l]) + (sred[2][l] + sred[3][l]);
    float rs = 1.0f / gs;

    // --- side outputs, one wave each (wave-uniform branch, no divergence) ---
    if (wu == 0) {
        o_idx[row] = (float)gi;
    } else if (wu == 1) {
        const float4* cg = reinterpret_cast<const float4*>(cb) + gi * (D / 4);
        float4* qv = reinterpret_cast<float4*>(o_quants) + (size_t)row * (D / 4);
        #pragma unroll
        for (int i = 0; i < D / 4; ++i) qv[i] = cg[i];
    } else if (wu == 2) {
        const float4* cg = reinterpret_cast<const float4*>(cb) + gi * (D / 4);
        float a0 = 0.f, a1 = 0.f, a2 = 0.f, a3 = 0.f;
        #pragma unroll
        for (int i = 0; i < D / 4; ++i) {
            float4 c = cg[i];
            float e0 = c.x - xr[4 * i + 0], e1 = c.y - xr[4 * i + 1];
            float e2 = c.z - xr[4 * i + 2], e3 = c.w - xr[4 * i + 3];
            a0 += e0 * e0; a1 += e1 * e1; a2 += e2 * e2; a3 += e3 * e3;
        }
        o_loss[row] = ((a0 + a1) + (a2 + a3)) * (1.25f / (float)D);
    }

    // --- probs: per-wave private LDS transpose (no barrier; same-wave DS is
    //     in-order), then fully line-coalesced 128B stores ---
    float4* op = reinterpret_cast<float4*>(o_probs);
    const int rowbase = blockIdx.x * ROWS;
    #pragma unroll
    for (int h = 0; h < 2; ++h) {          // two 32-code halves reuse the buffer
        #pragma unroll
        for (int i = 0; i < 8; ++i) {
            int j = h * 32 + i * 4;
            pbuf[wu][l][i] = make_float4(lg[j] * rs, lg[j + 1] * rs,
                                         lg[j + 2] * rs, lg[j + 3] * rs);
        }
        #pragma unroll
        for (int i = 0; i < 8; ++i) {
            int e  = i * 64 + l;
            int r  = e >> 3;       // 8 rows per instr
            int c4 = e & 7;        // 8 contiguous float4 = 128 B per row
            float4 v = pbuf[wu][r][c4];
            op[(size_t)(rowbase + r) * (K / 4) + wu * 16 + h * 8 + c4] = v;
        }
    }
}

extern "C" void kernel_launch(void* const* d_in, const int* in_sizes, int n_in,
                              void* d_out, int out_size, void* d_ws, size_t ws_size,
                              hipStream_t stream) {
    const float* x  = (const float*)d_in[0];
    const float* cb = (const float*)d_in[1];
    const int N = in_sizes[0] / D;   // 131072

    float* out      = (float*)d_out;
    float* o_idx    = out;
    float* o_probs  = o_idx + N;
    float* o_quants = o_probs + (size_t)N * K;
    float* o_loss   = o_quants + (size_t)N * D;

    const int grid = N / ROWS;   // 2048 blocks of 256 threads
    vq_kernel<<<grid, 256, 0, stream>>>(x, cb, o_idx, o_probs, o_quants, o_loss);
}

// Round 3
// 190.580 us; speedup vs baseline: 1.5245x; 1.5245x over previous
//
#include <hip/hip_runtime.h>
#include <math.h>

// x[32,4096,32] f32, codebook[256,32] f32
// outputs (concat f32): o_idx[N], o_probs[N*256], o_quants[N*32], o_loss[N]
constexpr int D    = 32;
constexpr int K    = 256;
constexpr int ROWS = 64;   // rows per block (= lanes per wave)
constexpr int WPB  = 8;    // waves per block (512 threads)
constexpr int CPT  = 32;   // codes per thread (K / WPB)

__global__ __launch_bounds__(512, 4) void vq_kernel(
    const float* __restrict__ x,
    const float* __restrict__ cb,
    float* __restrict__ o_idx,
    float* __restrict__ o_probs,
    float* __restrict__ o_quants,
    float* __restrict__ o_loss)
{
    // Union region: phase 1 = codebook (32 KB) + norms (1 KB); phase 2 = transpose
    // buffer pbuf[8][64][5] float4 (40 KB). Two barriers separate the phases.
    __shared__ __align__(16) char smem_u[40960];
    __shared__ float mred[WPB][ROWS];
    __shared__ float sred[WPB][ROWS];
    __shared__ int   ired[WPB][ROWS];

    float*  cbl  = reinterpret_cast<float*>(smem_u);            // [K*D]
    float*  cnl  = reinterpret_cast<float*>(smem_u + 32768);    // [K]
    float4* pbuf = reinterpret_cast<float4*>(smem_u);           // [8][64][5]

    const int tid = threadIdx.x;
    const int l   = tid & 63;          // lane = local row
    const int w   = tid >> 6;          // wave id (wave-uniform)
    const int row = blockIdx.x * ROWS + l;

    // --- stage codebook into LDS (coalesced, 2048 float4) ---
    {
        const float4* cg = reinterpret_cast<const float4*>(cb);
        float4*       cl = reinterpret_cast<float4*>(cbl);
        #pragma unroll
        for (int i = 0; i < 4; ++i) cl[tid + i * 512] = cg[tid + i * 512];
    }
    // --- per-code squared norm: 2 threads per code, pair-combine via shuffle ---
    {
        const int c = tid >> 1, h = tid & 1;
        const float4* p = reinterpret_cast<const float4*>(cb) + c * (D / 4) + h * 4;
        float a = 0.f;
        #pragma unroll
        for (int i = 0; i < 4; ++i) {
            float4 v = p[i];
            a += v.x * v.x + v.y * v.y + v.z * v.z + v.w * v.w;
        }
        a += __shfl_xor(a, 1);
        if (h == 0) cnl[c] = a;
    }

    // --- x row into registers ---
    float xr[D];
    {
        const float4* xv = reinterpret_cast<const float4*>(x) + (size_t)row * (D / 4);
        #pragma unroll
        for (int i = 0; i < D / 4; ++i) {
            float4 v = xv[i];
            xr[4 * i + 0] = v.x; xr[4 * i + 1] = v.y;
            xr[4 * i + 2] = v.z; xr[4 * i + 3] = v.w;
        }
    }
    float xx;
    {
        float a0 = 0.f, a1 = 0.f, a2 = 0.f, a3 = 0.f;
        #pragma unroll
        for (int j = 0; j < D; j += 4) {
            a0 += xr[j] * xr[j];         a1 += xr[j + 1] * xr[j + 1];
            a2 += xr[j + 2] * xr[j + 2]; a3 += xr[j + 3] * xr[j + 3];
        }
        xx = (a0 + a1) + (a2 + a3);
    }
    __syncthreads();   // cbl, cnl ready

    // --- distance pass: wave w covers codes [32w, 32w+32) ---
    // LDS reads are wave-uniform -> hardware broadcast (conflict-free, cheap),
    // value replicated into a VGPR -> every MAC is an all-VGPR v_fma_f32.
    const int kbase = w * CPT;
    const float4* cwl = reinterpret_cast<const float4*>(cbl) + kbase * (D / 4);
    float lg[CPT];
    #pragma unroll
    for (int j = 0; j < CPT; ++j) {
        float d0 = 0.f, d1 = 0.f, d2 = 0.f, d3 = 0.f;
        #pragma unroll
        for (int t = 0; t < D / 4; ++t) {
            float4 c4 = cwl[j * (D / 4) + t];
            d0 += xr[4 * t + 0] * c4.x; d1 += xr[4 * t + 1] * c4.y;
            d2 += xr[4 * t + 2] * c4.z; d3 += xr[4 * t + 3] * c4.w;
        }
        float dot = (d0 + d1) + (d2 + d3);
        lg[j] = 2.0f * dot - (xx + cnl[kbase + j]);   // = -d2
    }

    // --- local first-max argmax (strict > keeps lowest j) ---
    float m = lg[0]; int bi = 0;
    #pragma unroll
    for (int j = 1; j < CPT; ++j) {
        bool gt = lg[j] > m;
        m  = gt ? lg[j] : m;
        bi = gt ? j : bi;
    }
    mred[w][l] = m;
    ired[w][l] = kbase + bi;
    __syncthreads();   // also: last reads of cbl/cnl are done

    // --- cross-wave combine, ascending wave order keeps first occurrence ---
    float gm = mred[0][l]; int gi = ired[0][l];
    #pragma unroll
    for (int ww = 1; ww < WPB; ++ww) {
        float mw = mred[ww][l];
        bool gt  = mw > gm;
        gi = gt ? ired[ww][l] : gi;
        gm = gt ? mw : gm;
    }

    // --- exp in place + local sum ---
    float s = 0.f;
    #pragma unroll
    for (int j = 0; j < CPT; ++j) {
        float e = __expf(lg[j] - gm);
        lg[j] = e;
        s += e;
    }
    sred[w][l] = s;
    __syncthreads();   // after this barrier the union region may become pbuf

    float gs = 0.f;
    #pragma unroll
    for (int ww = 0; ww < WPB; ++ww) gs += sred[ww][l];
    const float rs = 1.0f / gs;

    // --- side outputs (wave-uniform branch) ---
    if (w == 4) {
        o_idx[row] = (float)gi;
    } else if (w == 5) {
        // loss = 1.25 * d2min / 32, and d2min = -gm  (free!)
        o_loss[row] = gm * (-1.25f / (float)D);
    } else if (w >= 6) {
        // quants = codebook[gi]; two waves split the 8 float4 (global cb, L2-hot)
        const int half = w - 6;   // 0 or 1
        const float4* cg = reinterpret_cast<const float4*>(cb) + gi * (D / 4) + half * 4;
        float4* qv = reinterpret_cast<float4*>(o_quants) + (size_t)row * (D / 4) + half * 4;
        #pragma unroll
        for (int i = 0; i < 4; ++i) qv[i] = cg[i];
    }

    // --- probs: per-wave private LDS transpose (same-wave DS ops are in-order),
    //     16-code halves, stores are 64B-contiguous segments ---
    float4* op = reinterpret_cast<float4*>(o_probs);
    const int rowbase = blockIdx.x * ROWS;
    #pragma unroll
    for (int h = 0; h < 2; ++h) {
        float4* pb = pbuf + ((size_t)w * ROWS + l) * 5;
        #pragma unroll
        for (int i = 0; i < 4; ++i) {
            int j = h * 16 + i * 4;
            pb[i] = make_float4(lg[j] * rs, lg[j + 1] * rs,
                                lg[j + 2] * rs, lg[j + 3] * rs);
        }
        #pragma unroll
        for (int i = 0; i < 4; ++i) {
            int e  = i * 64 + l;
            int r  = e >> 2;      // 4 float4 (16 codes) per row
            int c4 = e & 3;
            float4 v = pbuf[((size_t)w * ROWS + r) * 5 + c4];
            op[(size_t)(rowbase + r) * (K / 4) + w * 8 + h * 4 + c4] = v;
        }
    }
}

extern "C" void kernel_launch(void* const* d_in, const int* in_sizes, int n_in,
                              void* d_out, int out_size, void* d_ws, size_t ws_size,
                              hipStream_t stream) {
    const float* x  = (const float*)d_in[0];
    const float* cb = (const float*)d_in[1];
    const int N = in_sizes[0] / D;   // 131072

    float* out      = (float*)d_out;
    float* o_idx    = out;
    float* o_probs  = o_idx + N;
    float* o_quants = o_probs + (size_t)N * K;
    float* o_loss   = o_quants + (size_t)N * D;

    const int grid = N / ROWS;   // 2048 blocks of 512 threads
    vq_kernel<<<grid, 512, 0, stream>>>(x, cb, o_idx, o_probs, o_quants, o_loss);
}